// Round 4
// baseline (250.912 us; speedup 1.0000x reference)
//
#include <hip/hip_runtime.h>

#define THREADS 256
#define QPB 8            // queries per block (amortizes point scan, gives ILP)
#define KNN 32
#define CAP 512
#define MAXRETRY 34
#define NOTDONE 0xFFFFFFFFu

constexpr int Bc = 4, Nc = 8192, Sc = 2048, Cch = 64;

__device__ __forceinline__ unsigned dist2bits(float qx, float qy, float qz,
                                              float x, float y, float z) {
  // bit-exact vs numpy f32: no FMA contraction, fixed add order
  const float dx = __fsub_rn(qx, x);
  const float dy = __fsub_rn(qy, y);
  const float dz = __fsub_rn(qz, z);
  return __float_as_uint(__fadd_rn(
      __fadd_rn(__fmul_rn(dx, dx), __fmul_rn(dy, dy)), __fmul_rn(dz, dz)));
}

__global__ __launch_bounds__(THREADS) void neighbor_group_kernel(
    const float* __restrict__ xyz,      // (B, N, 3)
    const float* __restrict__ new_xyz,  // (B, S, 3)
    const float* __restrict__ feat,     // (B, N, C)
    float* __restrict__ out)
{
  __shared__ unsigned candDb[QPB][CAP];
  __shared__ unsigned candIdx[QPB][CAP];
  __shared__ unsigned winIdx[QPB][KNN];
  __shared__ unsigned winDb[QPB][KNN];
  __shared__ unsigned ccnt[QPB];
  __shared__ unsigned wavePiv[4][QPB];
  __shared__ unsigned sPiv[QPB], sLo[QPB], sHi[QPB], sForce[QPB], sC[QPB];
  __shared__ unsigned sDone;

  const int tid  = threadIdx.x;
  const int lane = tid & 63;
  const int wid  = tid >> 6;
  const int q0   = blockIdx.x * QPB;   // 8 queries, all in same batch (2048%8==0)
  const int b    = q0 >> 11;           // / S

  // query coords (block-uniform -> scalar regs)
  float qx[QPB], qy[QPB], qz[QPB];
#pragma unroll
  for (int qi = 0; qi < QPB; ++qi) {
    qx[qi] = new_xyz[(q0 + qi) * 3 + 0];
    qy[qi] = new_xyz[(q0 + qi) * 3 + 1];
    qz[qi] = new_xyz[(q0 + qi) * 3 + 2];
  }

  const float4* __restrict__ xb4 = (const float4*)(xyz + (size_t)b * Nc * 3);

  // ---- pass 1: per-thread min dist^2 bits per query ----
  unsigned lmin[QPB];
#pragma unroll
  for (int qi = 0; qi < QPB; ++qi) lmin[qi] = NOTDONE;
#pragma unroll
  for (int j2 = 0; j2 < 8; ++j2) {
    const int g = tid + j2 * THREADS;
    const float4 f0 = xb4[3 * g + 0];
    const float4 f1 = xb4[3 * g + 1];
    const float4 f2 = xb4[3 * g + 2];
    const float px[4] = {f0.x, f0.w, f1.z, f2.y};
    const float py[4] = {f0.y, f1.x, f1.w, f2.z};
    const float pz[4] = {f0.z, f1.y, f2.x, f2.w};
#pragma unroll
    for (int k = 0; k < 4; ++k) {
#pragma unroll
      for (int qi = 0; qi < QPB; ++qi) {
        const unsigned kb = dist2bits(qx[qi], qy[qi], qz[qi], px[k], py[k], pz[k]);
        lmin[qi] = min(lmin[qi], kb);
      }
    }
  }

  // ---- per-wave 8th-smallest of 64 mins via bitwise ballot select ----
#pragma unroll
  for (int qi = 0; qi < QPB; ++qi) {
    unsigned P = 0u;
#pragma unroll
    for (int bb = 30; bb >= 0; --bb) {
      const unsigned t = P | (1u << bb);
      if (__popcll(__ballot(lmin[qi] < t)) < 8) P = t;
    }
    if (lane == 0) wavePiv[wid][qi] = P + 1u;  // count(lmin < P+1) >= 8
  }
  __syncthreads();

  if (tid < QPB) {
    const unsigned p = max(max(wavePiv[0][tid], wavePiv[1][tid]),
                           max(wavePiv[2][tid], wavePiv[3][tid]));
    sPiv[tid] = p;            // >= 8 below per wave -> >= 32 block-wide
    sLo[tid] = 0u; sHi[tid] = 0xFFFFFFFFu; sForce[tid] = 0u;
    sC[tid] = NOTDONE;
  }

  // ---- pass 2: compaction (recompute dist^2); bisection retry if overflow --
  for (int it = 0; it < MAXRETRY; ++it) {
    __syncthreads();
    if (tid < QPB && sC[tid] == NOTDONE) ccnt[tid] = 0u;
    if (tid == 0) sDone = 1u;
    __syncthreads();

    unsigned piv[QPB];
#pragma unroll
    for (int qi = 0; qi < QPB; ++qi)
      piv[qi] = (sC[qi] == NOTDONE) ? sPiv[qi] : 0u;

#pragma unroll
    for (int j2 = 0; j2 < 8; ++j2) {
      const int g = tid + j2 * THREADS;
      const float4 f0 = xb4[3 * g + 0];
      const float4 f1 = xb4[3 * g + 1];
      const float4 f2 = xb4[3 * g + 2];
      const float px[4] = {f0.x, f0.w, f1.z, f2.y};
      const float py[4] = {f0.y, f1.x, f1.w, f2.z};
      const float pz[4] = {f0.z, f1.y, f2.x, f2.w};
#pragma unroll
      for (int k = 0; k < 4; ++k) {
        const unsigned pidx = (unsigned)(4 * g + k);
#pragma unroll
        for (int qi = 0; qi < QPB; ++qi) {
          const unsigned kb = dist2bits(qx[qi], qy[qi], qz[qi], px[k], py[k], pz[k]);
          if (kb < piv[qi]) {
            const unsigned pos = atomicAdd(&ccnt[qi], 1u);
            if (pos < CAP) { candDb[qi][pos] = kb; candIdx[qi][pos] = pidx; }
          }
        }
      }
    }
    __syncthreads();

    if (tid < QPB && sC[tid] == NOTDONE) {
      const unsigned c = ccnt[tid];
      if (sForce[tid] || (c >= KNN && c <= CAP)) {
        sC[tid] = min(c, (unsigned)CAP);
      } else {
        if (c < KNN) sLo[tid] = sPiv[tid]; else sHi[tid] = sPiv[tid];
        if (sHi[tid] - sLo[tid] <= 1u) { sPiv[tid] = sHi[tid]; sForce[tid] = 1u; }
        else sPiv[tid] = sLo[tid] + ((sHi[tid] - sLo[tid]) >> 1);
        sDone = 0u;
      }
    }
    __syncthreads();
    if (sDone) break;
  }

  // ---- sqrt only candidates (ranks/outputs use sqrt f32 bits + idx ties) ----
#pragma unroll
  for (int qi = 0; qi < QPB; ++qi) {
    const unsigned Cc = sC[qi];
    for (unsigned t = tid; t < Cc; t += THREADS)
      candDb[qi][t] =
          __float_as_uint(__fsqrt_rn(__uint_as_float(candDb[qi][t])));
  }
  __syncthreads();

  // ---- exact rank by (sqrt bits, idx); each wave handles 2 queries ----
#pragma unroll
  for (int rr = 0; rr < 2; ++rr) {
    const int qi = wid + rr * 4;
    const unsigned Cc = sC[qi];
    for (unsigned t = lane; t < Cc; t += 64) {
      const unsigned mdb = candDb[qi][t];
      const unsigned mix = candIdx[qi][t];
      unsigned rank = 0u;
      for (unsigned o = 0; o < Cc; ++o) {
        const unsigned odb = candDb[qi][o];
        const unsigned oix = candIdx[qi][o];
        rank += (odb < mdb || (odb == mdb && oix < mix)) ? 1u : 0u;
      }
      if (rank < KNN) { winIdx[qi][rank] = mix; winDb[qi][rank] = mdb; }
    }
  }
  __syncthreads();

  // ---- outputs (flat concat: nxyz | idxs | nfeat | values), all f32 ----
  float* out_nx = out;                                   // B*S*K*3
  float* out_id = out + (size_t)Bc * Sc * KNN * 3;       // B*S*K
  float* out_nf = out_id + (size_t)Bc * Sc * KNN;        // B*S*K*C
  float* out_sv = out_nf + (size_t)Bc * Sc * KNN * Cch;  // B*S*K

  const float* xb = xyz + (size_t)b * Nc * 3;
  const float4* fb4 = (const float4*)(feat + (size_t)b * Nc * Cch);

#pragma unroll
  for (int qi = 0; qi < QPB; ++qi) {
    const int q = q0 + qi;
    if (tid < KNN) {
      out_id[(size_t)q * KNN + tid] = (float)winIdx[qi][tid];
      out_sv[(size_t)q * KNN + tid] = __uint_as_float(winDb[qi][tid]);
    }
    if (tid < KNN * 3) {
      const int w = tid / 3, c3 = tid % 3;
      out_nx[((size_t)q * KNN + w) * 3 + c3] =
          xb[(size_t)winIdx[qi][w] * 3 + c3];
    }
    float4* onf4 = (float4*)(out_nf + (size_t)q * KNN * Cch);
#pragma unroll
    for (int r = 0; r < 2; ++r) {
      const int flat = tid + r * THREADS;   // 0..511
      const int w = flat >> 4;              // winner 0..31
      const int c4 = flat & 15;
      onf4[w * 16 + c4] = fb4[(size_t)winIdx[qi][w] * 16 + c4];
    }
  }
}

extern "C" void kernel_launch(void* const* d_in, const int* in_sizes, int n_in,
                              void* d_out, int out_size, void* d_ws, size_t ws_size,
                              hipStream_t stream) {
  const float* xyz     = (const float*)d_in[0];
  const float* new_xyz = (const float*)d_in[1];
  const float* feat    = (const float*)d_in[2];
  float* out = (float*)d_out;

  const int grid = (Bc * Sc) / QPB;  // 1024 blocks, 8 queries each
  neighbor_group_kernel<<<grid, THREADS, 0, stream>>>(xyz, new_xyz, feat, out);
}

// Round 5
// 176.352 us; speedup vs baseline: 1.4228x; 1.4228x over previous
//
#include <hip/hip_runtime.h>

#define THREADS 512
#define QPB 2            // queries per block
#define KNN 32
#define CAP 512
#define MAXRETRY 34
#define NOTDONE 0xFFFFFFFFu

constexpr int Bc = 4, Nc = 8192, Sc = 2048, Cch = 64;

__device__ __forceinline__ unsigned dist2bits(float qx, float qy, float qz,
                                              float x, float y, float z) {
  // bit-exact vs numpy f32: no FMA contraction, fixed add order
  const float dx = __fsub_rn(qx, x);
  const float dy = __fsub_rn(qy, y);
  const float dz = __fsub_rn(qz, z);
  return __float_as_uint(__fadd_rn(
      __fadd_rn(__fmul_rn(dx, dx), __fmul_rn(dy, dy)), __fmul_rn(dz, dz)));
}

__global__ __launch_bounds__(THREADS) void neighbor_group_kernel(
    const float* __restrict__ xyz,      // (B, N, 3)
    const float* __restrict__ new_xyz,  // (B, S, 3)
    const float* __restrict__ feat,     // (B, N, C)
    float* __restrict__ out)
{
  __shared__ uint4 keys4[QPB][Nc / 4];          // 64 KB: all dist^2 bits
  __shared__ unsigned candDb[QPB][CAP];
  __shared__ unsigned candIdx[QPB][CAP];
  __shared__ unsigned winIdx[QPB][KNN];
  __shared__ unsigned winDb[QPB][KNN];
  __shared__ unsigned ccnt[QPB];
  __shared__ unsigned wavePiv[8][QPB];
  __shared__ unsigned sPiv[QPB], sLo[QPB], sHi[QPB], sForce[QPB], sC[QPB];
  __shared__ unsigned sDone;

  const int tid  = threadIdx.x;
  const int lane = tid & 63;
  const int wid  = tid >> 6;                    // 0..7
  const int q0   = blockIdx.x * QPB;
  const int b    = q0 >> 11;                    // / S (S = 2048)

  float qx[QPB], qy[QPB], qz[QPB];
#pragma unroll
  for (int qi = 0; qi < QPB; ++qi) {
    qx[qi] = new_xyz[(q0 + qi) * 3 + 0];
    qy[qi] = new_xyz[(q0 + qi) * 3 + 1];
    qz[qi] = new_xyz[(q0 + qi) * 3 + 2];
  }

  const float4* __restrict__ xb4 = (const float4*)(xyz + (size_t)b * Nc * 3);

  // ---- single distance pass: keys -> LDS, track per-thread min ----
  unsigned lmin[QPB];
#pragma unroll
  for (int qi = 0; qi < QPB; ++qi) lmin[qi] = NOTDONE;
#pragma unroll
  for (int j2 = 0; j2 < Nc / 4 / THREADS; ++j2) {   // 4 iterations
    const int g = tid + j2 * THREADS;               // group of 4 points
    const float4 f0 = xb4[3 * g + 0];
    const float4 f1 = xb4[3 * g + 1];
    const float4 f2 = xb4[3 * g + 2];
    const float px[4] = {f0.x, f0.w, f1.z, f2.y};
    const float py[4] = {f0.y, f1.x, f1.w, f2.z};
    const float pz[4] = {f0.z, f1.y, f2.x, f2.w};
    unsigned kk[QPB][4];
#pragma unroll
    for (int k = 0; k < 4; ++k) {
#pragma unroll
      for (int qi = 0; qi < QPB; ++qi) {
        const unsigned kb =
            dist2bits(qx[qi], qy[qi], qz[qi], px[k], py[k], pz[k]);
        kk[qi][k] = kb;
        lmin[qi] = min(lmin[qi], kb);
      }
    }
#pragma unroll
    for (int qi = 0; qi < QPB; ++qi)
      keys4[qi][g] = make_uint4(kk[qi][0], kk[qi][1], kk[qi][2], kk[qi][3]);
  }

  // ---- per-wave 4th-smallest of 64 thread-mins via bitwise ballot select ---
  // largest P with count(lmin < P) < 4; pivot = P+1 -> >=4/wave -> >=32 block
#pragma unroll
  for (int qi = 0; qi < QPB; ++qi) {
    unsigned P = 0u;
#pragma unroll
    for (int bb = 30; bb >= 0; --bb) {
      const unsigned t = P | (1u << bb);
      if (__popcll(__ballot(lmin[qi] < t)) < 4) P = t;
    }
    if (lane == 0) wavePiv[wid][qi] = P + 1u;
  }
  __syncthreads();

  if (tid < QPB) {
    unsigned p = wavePiv[0][tid];
#pragma unroll
    for (int w = 1; w < 8; ++w) p = max(p, wavePiv[w][tid]);
    sPiv[tid] = p;
    sLo[tid] = 0u; sHi[tid] = NOTDONE; sForce[tid] = 0u;
    sC[tid] = NOTDONE;
  }

  // ---- compaction: sweep LDS keys; bisection retry (LDS-only) if overflow --
  for (int it = 0; it < MAXRETRY; ++it) {
    __syncthreads();
    if (tid < QPB && sC[tid] == NOTDONE) ccnt[tid] = 0u;
    if (tid == 0) sDone = 1u;
    __syncthreads();
#pragma unroll
    for (int qi = 0; qi < QPB; ++qi) {
      if (sC[qi] != NOTDONE) continue;        // block-uniform branch
      const unsigned piv = sPiv[qi];
#pragma unroll
      for (int j2 = 0; j2 < Nc / 4 / THREADS; ++j2) {
        const int g = tid + j2 * THREADS;
        const uint4 kk = keys4[qi][g];
        const unsigned ks[4] = {kk.x, kk.y, kk.z, kk.w};
#pragma unroll
        for (int k = 0; k < 4; ++k) {
          if (ks[k] < piv) {
            const unsigned pos = atomicAdd(&ccnt[qi], 1u);
            if (pos < CAP) {
              candDb[qi][pos]  = ks[k];
              candIdx[qi][pos] = (unsigned)(4 * g + k);
            }
          }
        }
      }
    }
    __syncthreads();
    if (tid < QPB && sC[tid] == NOTDONE) {
      const unsigned c = ccnt[tid];
      if (sForce[tid] || (c >= KNN && c <= CAP)) {
        sC[tid] = min(c, (unsigned)CAP);
      } else {
        if (c < KNN) sLo[tid] = sPiv[tid]; else sHi[tid] = sPiv[tid];
        if (sHi[tid] - sLo[tid] <= 1u) { sPiv[tid] = sHi[tid]; sForce[tid] = 1u; }
        else sPiv[tid] = sLo[tid] + ((sHi[tid] - sLo[tid]) >> 1);
        sDone = 0u;
      }
    }
    __syncthreads();
    if (sDone) break;
  }

  // ---- sqrt only candidates (numpy ranks use sqrt f32 bits + idx ties) ----
#pragma unroll
  for (int qi = 0; qi < QPB; ++qi) {
    const unsigned Cc = sC[qi];
    for (unsigned t = tid; t < Cc; t += THREADS)
      candDb[qi][t] =
          __float_as_uint(__fsqrt_rn(__uint_as_float(candDb[qi][t])));
  }
  __syncthreads();

  // ---- exact rank by (sqrt bits, idx) lexicographic; ranks unique ----
#pragma unroll
  for (int qi = 0; qi < QPB; ++qi) {
    const unsigned Cc = sC[qi];
    for (unsigned t = tid; t < Cc; t += THREADS) {
      const unsigned mdb = candDb[qi][t];
      const unsigned mix = candIdx[qi][t];
      unsigned rank = 0u;
      for (unsigned o = 0; o < Cc; ++o) {
        const unsigned odb = candDb[qi][o];
        const unsigned oix = candIdx[qi][o];
        rank += (odb < mdb || (odb == mdb && oix < mix)) ? 1u : 0u;
      }
      if (rank < KNN) { winIdx[qi][rank] = mix; winDb[qi][rank] = mdb; }
    }
  }
  __syncthreads();

  // ---- outputs (flat concat: nxyz | idxs | nfeat | values), all f32 ----
  float* out_nx = out;                                   // B*S*K*3
  float* out_id = out + (size_t)Bc * Sc * KNN * 3;       // B*S*K
  float* out_nf = out_id + (size_t)Bc * Sc * KNN;        // B*S*K*C
  float* out_sv = out_nf + (size_t)Bc * Sc * KNN * Cch;  // B*S*K

  const float* xb = xyz + (size_t)b * Nc * 3;
  const float4* fb4 = (const float4*)(feat + (size_t)b * Nc * Cch);

#pragma unroll
  for (int qi = 0; qi < QPB; ++qi) {
    const int q = q0 + qi;
    if (tid < KNN) {
      out_id[(size_t)q * KNN + tid] = (float)winIdx[qi][tid];
      out_sv[(size_t)q * KNN + tid] = __uint_as_float(winDb[qi][tid]);
    }
    if (tid < KNN * 3) {
      const int w = tid / 3, c3 = tid % 3;
      out_nx[((size_t)q * KNN + w) * 3 + c3] =
          xb[(size_t)winIdx[qi][w] * 3 + c3];
    }
    // feature gather: 32 winners x 16 float4 = 512 float4 = one full round
    float4* onf4 = (float4*)(out_nf + (size_t)q * KNN * Cch);
    const int w = tid >> 4;         // winner 0..31
    const int c4 = tid & 15;
    onf4[w * 16 + c4] = fb4[(size_t)winIdx[qi][w] * 16 + c4];
  }
}

extern "C" void kernel_launch(void* const* d_in, const int* in_sizes, int n_in,
                              void* d_out, int out_size, void* d_ws, size_t ws_size,
                              hipStream_t stream) {
  const float* xyz     = (const float*)d_in[0];
  const float* new_xyz = (const float*)d_in[1];
  const float* feat    = (const float*)d_in[2];
  float* out = (float*)d_out;

  const int grid = (Bc * Sc) / QPB;  // 4096 blocks, 2 queries each
  neighbor_group_kernel<<<grid, THREADS, 0, stream>>>(xyz, new_xyz, feat, out);
}

// Round 6
// 70.033 us; speedup vs baseline: 3.5828x; 2.5181x over previous
//
#include <hip/hip_runtime.h>

#define THREADS 256
#define KNN 32
#define CAP 256
#define MAXRETRY 33

constexpr int Bc = 4, Nc = 8192, Sc = 2048, Cch = 64;

__device__ __forceinline__ unsigned dist2bits(float qx, float qy, float qz,
                                              float x, float y, float z) {
  // bit-exact vs numpy f32: no FMA contraction, fixed op order
  const float dx = __fsub_rn(qx, x);
  const float dy = __fsub_rn(qy, y);
  const float dz = __fsub_rn(qz, z);
  return __float_as_uint(__fadd_rn(
      __fadd_rn(__fmul_rn(dx, dx), __fmul_rn(dy, dy)), __fmul_rn(dz, dz)));
}

__global__ __launch_bounds__(THREADS, 4) void neighbor_group_kernel(
    const float* __restrict__ xyz,      // (B, N, 3)
    const float* __restrict__ new_xyz,  // (B, S, 3)
    const float* __restrict__ feat,     // (B, N, C)
    float* __restrict__ out)
{
  __shared__ unsigned candDb[CAP];
  __shared__ unsigned candIdx[CAP];
  __shared__ unsigned winIdx[KNN];
  __shared__ unsigned winDb[KNN];
  __shared__ unsigned wavePiv[4];
  __shared__ unsigned ccnt;

  const int tid  = threadIdx.x;
  const int lane = tid & 63;
  const int wid  = tid >> 6;
  const int q    = blockIdx.x;          // one query per block
  const int b    = q >> 11;             // / S (S = 2048)

  const float qx = new_xyz[q * 3 + 0];
  const float qy = new_xyz[q * 3 + 1];
  const float qz = new_xyz[q * 3 + 2];

  const float4* __restrict__ xb4 = (const float4*)(xyz + (size_t)b * Nc * 3);

  // ---- single distance pass: keys in REGISTERS, track per-thread min ----
  unsigned keys[32];
  unsigned lmin = 0xFFFFFFFFu;
#pragma unroll
  for (int j2 = 0; j2 < 8; ++j2) {
    const int g = tid + j2 * THREADS;   // group of 4 consecutive points
    const float4 f0 = xb4[3 * g + 0];
    const float4 f1 = xb4[3 * g + 1];
    const float4 f2 = xb4[3 * g + 2];
    const float px[4] = {f0.x, f0.w, f1.z, f2.y};
    const float py[4] = {f0.y, f1.x, f1.w, f2.z};
    const float pz[4] = {f0.z, f1.y, f2.x, f2.w};
#pragma unroll
    for (int k = 0; k < 4; ++k) {
      const unsigned kb = dist2bits(qx, qy, qz, px[k], py[k], pz[k]);
      keys[j2 * 4 + k] = kb;
      lmin = min(lmin, kb);
    }
  }

  // ---- per-wave 8th-smallest of 64 lane-mins via bitwise ballot select ----
  // largest P with count(lmin < P) < 8; pivot = P+1 -> >=8/wave -> >=32 block
  unsigned P = 0u;
#pragma unroll
  for (int bb = 30; bb >= 0; --bb) {
    const unsigned t = P | (1u << bb);
    if (__popcll(__ballot(lmin < t)) < 8) P = t;
  }
  if (lane == 0) wavePiv[wid] = P + 1u;
  if (tid == 0) ccnt = 0u;
  __syncthreads();

  unsigned piv = max(max(wavePiv[0], wavePiv[1]),
                     max(wavePiv[2], wavePiv[3]));

  // ---- compaction (register sweep); rare bisection retry on overflow ----
  unsigned C = 0;
  unsigned lo = 0u, hi = 0xFFFFFFFFu;
  bool force = false;
  for (int it = 0; it < MAXRETRY; ++it) {
#pragma unroll
    for (int j = 0; j < 32; ++j) {
      if (keys[j] < piv) {
        const unsigned pos = atomicAdd(&ccnt, 1u);
        if (pos < CAP) {
          candDb[pos]  = keys[j];
          // point index: p = 4*tid + (j>>2)*1024 + (j&3)
          candIdx[pos] = (unsigned)(4 * tid + (j >> 2) * 1024 + (j & 3));
        }
      }
    }
    __syncthreads();
    const unsigned c = ccnt;            // block-uniform
    if (force || (c >= KNN && c <= CAP)) { C = min(c, (unsigned)CAP); break; }
    if (c < KNN) lo = piv; else hi = piv;
    if (hi - lo <= 1u) { piv = hi; force = true; }
    else piv = lo + ((hi - lo) >> 1);
    __syncthreads();
    if (tid == 0) ccnt = 0u;
    __syncthreads();
  }

  // ---- sqrt only candidates (numpy ranks use sqrt f32 bits + idx ties) ----
  for (unsigned t = tid; t < C; t += THREADS)
    candDb[t] = __float_as_uint(__fsqrt_rn(__uint_as_float(candDb[t])));
  __syncthreads();

  // ---- exact rank by (sqrt bits, idx); C <= 256 -> 1 candidate/thread ----
  for (unsigned t = tid; t < C; t += THREADS) {
    const unsigned mdb = candDb[t];
    const unsigned mix = candIdx[t];
    unsigned rank = 0u;
    for (unsigned o = 0; o < C; ++o) {   // candDb[o]: same addr -> broadcast
      const unsigned odb = candDb[o];
      const unsigned oix = candIdx[o];
      rank += (odb < mdb || (odb == mdb && oix < mix)) ? 1u : 0u;
    }
    if (rank < KNN) { winIdx[rank] = mix; winDb[rank] = mdb; }
  }
  __syncthreads();

  // ---- outputs (flat concat: nxyz | idxs | nfeat | values), all f32 ----
  float* out_nx = out;                                   // B*S*K*3
  float* out_id = out + (size_t)Bc * Sc * KNN * 3;       // B*S*K
  float* out_nf = out_id + (size_t)Bc * Sc * KNN;        // B*S*K*C
  float* out_sv = out_nf + (size_t)Bc * Sc * KNN * Cch;  // B*S*K

  const float* xb = xyz + (size_t)b * Nc * 3;
  const float4* fb4 = (const float4*)(feat + (size_t)b * Nc * Cch);

  if (tid < KNN) {
    out_id[(size_t)q * KNN + tid] = (float)winIdx[tid];
    out_sv[(size_t)q * KNN + tid] = __uint_as_float(winDb[tid]);
  }
  if (tid < KNN * 3) {
    const int w = tid / 3, c3 = tid % 3;
    out_nx[((size_t)q * KNN + w) * 3 + c3] = xb[(size_t)winIdx[w] * 3 + c3];
  }
  // feature gather: 32 winners x 16 float4 = 512 float4 -> 2 rounds
  float4* onf4 = (float4*)(out_nf + (size_t)q * KNN * Cch);
#pragma unroll
  for (int r = 0; r < 2; ++r) {
    const int flat = tid + r * THREADS;   // 0..511
    const int w = flat >> 4;              // winner 0..31
    const int c4 = flat & 15;
    onf4[w * 16 + c4] = fb4[(size_t)winIdx[w] * 16 + c4];
  }
}

extern "C" void kernel_launch(void* const* d_in, const int* in_sizes, int n_in,
                              void* d_out, int out_size, void* d_ws, size_t ws_size,
                              hipStream_t stream) {
  const float* xyz     = (const float*)d_in[0];
  const float* new_xyz = (const float*)d_in[1];
  const float* feat    = (const float*)d_in[2];
  float* out = (float*)d_out;

  const int grid = Bc * Sc;  // 8192 blocks, 1 query each
  neighbor_group_kernel<<<grid, THREADS, 0, stream>>>(xyz, new_xyz, feat, out);
}